// Round 1
// baseline (291.731 us; speedup 1.0000x reference)
//
#include <hip/hip_runtime.h>

// MemoryReader: B=4, CK=64, N=8192, M=1024, CV=512. Inputs fp32, output fp32.
// logits s[n,m] = (2*mk.qk - |mk|^2)/8; softmax over n; out = mv @ P.
// R8: fused single k_main, 292us total / 197us k_main. Latency-bound: MfmaUtil 14%,
//     VALU 30%, HBM 2%, 8.4M LDS bank conflicts (P b16 stores quad-alias 4-way).
// R9: (a) mv register-prefetch one step ahead (issued with ktile prefetch after
//     barrier1, consumed from regs next step -> GEMM2 touches no vmem);
//     (b) mv loaded fp32 + in-reg bf16 convert -> k_mvconv deleted (96MiB traffic);
//     (c) GEMM1 MFMA operands swapped (A=K,B=Q; identical frag layouts) so D is
//     [n=quad*4+r][m=l15]: P store = one aligned ds_write_b64 per nt, bank
//     pattern 4*l15+2*quad conflict-free; dpart 4->1 reg, denom = 2 shfls;
//     (d) k_prep 4 threads/token (512 blocks, 16 loads/thread).

typedef unsigned short ushort_t;
typedef unsigned int uint_t;
typedef __attribute__((ext_vector_type(8))) short short8;
typedef __attribute__((ext_vector_type(4))) float floatx4;

#define MFMA16(a, b, c) __builtin_amdgcn_mfma_f32_16x16x32_bf16((a), (b), (c), 0, 0, 0)

__device__ __forceinline__ ushort_t f2b(float f) {
    uint_t b = __float_as_uint(f);
    b += 0x7FFFu + ((b >> 16) & 1u);   // RNE to bf16
    return (ushort_t)(b >> 16);
}

#define BB 4
#define CK 64
#define NN 8192
#define MM 1024
#define CV 512
#define NSTEP 128     // 64-token steps over full n-range

// ---- module-scope scratch (fully rewritten every call) ----
__device__ __align__(16) ushort_t g_mkT[BB * NN * CK];   // 4 MiB  bf16 mk^T [b][n][c]
__device__ __align__(16) float    g_asq8[BB * NN];       // 128 KiB (sum mk^2)/8

// ---------------------------------------------------------------------------
// K0: g_mkT[b][n][c] = bf16(mk[b][c][n]); g_asq8 = (sum_c mk^2)/8 in fp32.
// 4 threads per token (c-quarters), shfl-combined |a|^2. 512 blocks.
// ---------------------------------------------------------------------------
__global__ __launch_bounds__(256) void k_prep(const float* __restrict__ mk) {
    int t = blockIdx.x * 256 + threadIdx.x;   // 0 .. 4*B*N-1
    int token = t >> 2;
    int qd = t & 3;                           // c-quarter 0..3
    int b = token >> 13;
    int n = token & (NN - 1);
    const float* src = mk + (size_t)b * CK * NN + (size_t)(qd * 16) * NN + n;
    ushort_t* dst = g_mkT + (size_t)token * CK + qd * 16;
    float acc = 0.f;
#pragma unroll
    for (int g = 0; g < 2; g++) {
        float f[8];
#pragma unroll
        for (int i = 0; i < 8; i++) {
            f[i] = src[(size_t)(g * 8 + i) * NN];
            acc += f[i] * f[i];
        }
        uint4 q;
        q.x = (uint_t)f2b(f[0]) | ((uint_t)f2b(f[1]) << 16);
        q.y = (uint_t)f2b(f[2]) | ((uint_t)f2b(f[3]) << 16);
        q.z = (uint_t)f2b(f[4]) | ((uint_t)f2b(f[5]) << 16);
        q.w = (uint_t)f2b(f[6]) | ((uint_t)f2b(f[7]) << 16);
        *(uint4*)(dst + g * 8) = q;
    }
    acc += __shfl_xor(acc, 1, 64);
    acc += __shfl_xor(acc, 2, 64);
    if (qd == 0) g_asq8[token] = acc * 0.125f;
}

// ---------------------------------------------------------------------------
// K1: fused everything. grid 512 = mt16(16) x cs(8) x b(4), bx = mt16*32+cs*4+b.
// Per 64-token step:
//   GEMM1 (A=K-frags from LDS, B=Q-frags in regs) -> exp -> P bf16 b64-stores +
//   denom partial; barrier1; prefetch next ktile (gl_lds) + next-step mv fp32 ->
//   regs; GEMM2 (reg-held mv converted to bf16 x P from LDS) -> acc; barrier2
//   (drains prefetches). Epilogue: denom shfl-reduce, divide, store fp32.
// MFMA frag layouts (m89/m91): A[row=lane&15][k=quad*8+j], B[k][col=lane&15]
// (same per-lane reg layout), D[row=quad*4+r][col=lane&15].
// ---------------------------------------------------------------------------

#define STAGE(bufidx, nbase) do {                                                     \
    _Pragma("unroll")                                                                 \
    for (int gi = 0; gi < 2; gi++) {                                                  \
        int g2 = w + gi * 4;                                                          \
        const ushort_t* gsrc = mkTb + (size_t)((nbase) + lane) * CK + g2 * 8;         \
        ushort_t* ldst = &ktile[bufidx][g2 * 512];                                    \
        __builtin_amdgcn_global_load_lds(                                             \
            (const __attribute__((address_space(1))) unsigned int*)gsrc,              \
            (__attribute__((address_space(3))) unsigned int*)ldst, 16, 0, 0);         \
    }                                                                                 \
    if (w == 0) {                                                                     \
        const float* as = g_asq8 + (size_t)b * NN + (nbase) + lane;                   \
        __builtin_amdgcn_global_load_lds(                                             \
            (const __attribute__((address_space(1))) unsigned int*)as,                \
            (__attribute__((address_space(3))) unsigned int*)&asq_s[bufidx][0], 4, 0, 0); \
    }                                                                                 \
} while (0)

__device__ __forceinline__ short8 pack8(floatx4 a, floatx4 b) {
    short8 r;
    r[0] = (short)f2b(a[0]); r[1] = (short)f2b(a[1]);
    r[2] = (short)f2b(a[2]); r[3] = (short)f2b(a[3]);
    r[4] = (short)f2b(b[0]); r[5] = (short)f2b(b[1]);
    r[6] = (short)f2b(b[2]); r[7] = (short)f2b(b[3]);
    return r;
}

// One 64-token step. bufc: compile-time ktile buffer (0/1). VCUR: this step's mv
// fp32 regs (loaded last step). VNXT: regs to prefetch next step's mv into.
#define STEP_BODY(bufc, VCUR, VNXT, stepv) do {                                       \
    /* ---- GEMM1: scores -> exp -> P(bf16) b64 stores + denom partial ---- */        \
    _Pragma("unroll")                                                                 \
    for (int nt = 0; nt < 4; nt++) {                                                  \
        const ushort_t* kr = &ktile[bufc][(quad * 64 + nt * 16 + l15) * 8];           \
        short8 kb0 = *(const short8*)kr;                                              \
        short8 kb1 = *(const short8*)(kr + 2048);   /* cq+4 */                        \
        floatx4 d = (floatx4){0.f, 0.f, 0.f, 0.f};                                    \
        d = MFMA16(kb0, aq0, d);                                                      \
        d = MFMA16(kb1, aq1, d);                                                      \
        floatx4 sa4 = *(const floatx4*)&asq_s[bufc][nt * 16 + quad * 4];              \
        float p0 = __expf(d[0] * 0.25f - sa4[0]);                                     \
        float p1 = __expf(d[1] * 0.25f - sa4[1]);                                     \
        float p2 = __expf(d[2] * 0.25f - sa4[2]);                                     \
        float p3 = __expf(d[3] * 0.25f - sa4[3]);                                     \
        dpart += (p0 + p1) + (p2 + p3);                                               \
        uint2 pk;                                                                     \
        pk.x = (uint_t)f2b(p0) | ((uint_t)f2b(p1) << 16);                             \
        pk.y = (uint_t)f2b(p2) | ((uint_t)f2b(p3) << 16);                             \
        *(uint2*)&lds_p[(w * 16 + l15) * 72 + nt * 16 + quad * 4] = pk;               \
    }                                                                                 \
    __syncthreads();   /* P ready (nothing outstanding on vmcnt here) */              \
    if ((stepv) + 1 < NSTEP) {                                                        \
        STAGE((bufc) ^ 1, ((stepv) + 1) * 64);                                        \
        const float* vp = vsrc + ((size_t)(stepv) + 1) * 64;                          \
        VNXT[0] = *(const floatx4*)(vp);                                              \
        VNXT[1] = *(const floatx4*)(vp + 4);                                          \
        VNXT[2] = *(const floatx4*)(vp + 32);                                         \
        VNXT[3] = *(const floatx4*)(vp + 36);                                         \
    }                                                                                 \
    /* ---- GEMM2: acc[c 16/wave][m 64] += mv-tile(regs) x P-tile(LDS) ---- */        \
    _Pragma("unroll")                                                                 \
    for (int kc = 0; kc < 2; kc++) {                                                  \
        short8 vv = pack8(VCUR[kc * 2], VCUR[kc * 2 + 1]);                            \
        short8 pb[4];                                                                 \
        _Pragma("unroll")                                                             \
        for (int mt = 0; mt < 4; mt++)                                                \
            pb[mt] = *(const short8*)&lds_p[(mt * 16 + l15) * 72 + kc * 32 + quad * 8]; \
        _Pragma("unroll")                                                             \
        for (int mt = 0; mt < 4; mt++) acc[mt] = MFMA16(vv, pb[mt], acc[mt]);         \
    }                                                                                 \
    __syncthreads();   /* P consumed; vmcnt(0) -> next ktile + next mv landed */      \
} while (0)

__global__ __launch_bounds__(256, 2) void k_main(const float* __restrict__ qk,
                                                 const float* __restrict__ mv,
                                                 float* __restrict__ out) {
    __shared__ __align__(16) ushort_t ktile[2][64 * 64];   // 2 x 8 KiB
    __shared__ __align__(16) ushort_t lds_p[64 * 72];      // 9 KiB, [m][n] pitch 72
    __shared__ __align__(16) float    asq_s[2][64];
    __shared__ float denom_s[64];

    int bx = blockIdx.x;
    int mt16 = bx >> 5;          // 0..15
    int cs = (bx >> 2) & 7;      // 0..7
    int b = bx & 3;              // 0..3
    int c0 = cs * 64;
    int m0 = mt16 * 64;

    int tid = threadIdx.x;
    int w = tid >> 6;
    int lane = tid & 63;
    int quad = lane >> 4;
    int l15 = lane & 15;

    // Q fragments (16 m-cols per wave, K=64), held in regs all loop.
    int mrow = m0 + w * 16 + l15;
    short8 aq0, aq1;
#pragma unroll
    for (int j = 0; j < 8; j++) {
        aq0[j] = (short)f2b(qk[(size_t)(b * CK + quad * 8 + j) * MM + mrow]);
        aq1[j] = (short)f2b(qk[(size_t)(b * CK + 32 + quad * 8 + j) * MM + mrow]);
    }

    const ushort_t* mkTb = g_mkT + (size_t)b * NN * CK;
    const float* vsrc = mv + (size_t)(b * CV + c0 + w * 16 + l15) * NN + quad * 8;

    floatx4 acc[4];
#pragma unroll
    for (int j = 0; j < 4; j++) acc[j] = (floatx4){0.f, 0.f, 0.f, 0.f};
    float dpart = 0.f;

    floatx4 vaA[4], vaB[4];

    // ---- prologue: stage ktile[0] + asq[0]; mv for step 0 -> vaA ----
    STAGE(0, 0);
    vaA[0] = *(const floatx4*)(vsrc);
    vaA[1] = *(const floatx4*)(vsrc + 4);
    vaA[2] = *(const floatx4*)(vsrc + 32);
    vaA[3] = *(const floatx4*)(vsrc + 36);
    __syncthreads();   // vmcnt(0) drain -> ktile[0]/asq[0]/vaA ready

    for (int sp = 0; sp < NSTEP / 2; sp++) {
        STEP_BODY(0, vaA, vaB, sp * 2);
        STEP_BODY(1, vaB, vaA, sp * 2 + 1);
    }

    // ---- epilogue: denom shfl-reduce across quads, normalize, store fp32 ----
    dpart += __shfl_xor(dpart, 16, 64);
    dpart += __shfl_xor(dpart, 32, 64);
    if (lane < 16) denom_s[w * 16 + l15] = dpart;
    __syncthreads();

#pragma unroll
    for (int mt = 0; mt < 4; mt++) {
        float rdm = 1.0f / denom_s[mt * 16 + l15];
#pragma unroll
        for (int r = 0; r < 4; r++) {
            size_t o = (size_t)(b * CV + c0 + w * 16 + quad * 4 + r) * MM + m0 + mt * 16 + l15;
            out[o] = acc[mt][r] * rdm;
        }
    }
}

// ---------------------------------------------------------------------------
// launch — inputs identified BY SIZE.
// ---------------------------------------------------------------------------
extern "C" void kernel_launch(void* const* d_in, const int* in_sizes, int n_in,
                              void* d_out, int out_size, void* d_ws, size_t ws_size,
                              hipStream_t stream) {
    const float* mk = nullptr;   // 2,097,152
    const float* qk = nullptr;   //   262,144
    const float* mv = nullptr;   // 16,777,216
    for (int i = 0; i < n_in; i++) {
        if (in_sizes[i] == BB * CK * NN)      mk = (const float*)d_in[i];
        else if (in_sizes[i] == BB * CK * MM) qk = (const float*)d_in[i];
        else if (in_sizes[i] == BB * CV * NN) mv = (const float*)d_in[i];
    }
    float* out = (float*)d_out;
    (void)d_ws; (void)ws_size; (void)out_size;

    k_prep<<<(BB * NN * 4) / 256, 256, 0, stream>>>(mk);
    k_main<<<16 * 8 * BB, 256, 0, stream>>>(qk, mv, out);
}

// Round 7
// 271.745 us; speedup vs baseline: 1.0735x; 1.0735x over previous
//
#include <hip/hip_runtime.h>

// MemoryReader: B=4, CK=64, N=8192, M=1024, CV=512. Inputs fp32, output fp32.
// logits s[n,m] = (2*mk.qk - |mk|^2)/8; softmax over n; out = mv @ P.
// R8: 197us k_main, PASSED (LDS ktile + P-LDS + g_mvb bf16).
// R9: 228us, PASSED (mv fp32->regs + pack8 GEMM2 = pinned).
// R10-R12: LDS-free k_main (swapped GEMM1, fused K=32 GEMM2, cvt_pk asm) FAILED
//   deterministically (absmax 3.1445, identical across two different k_preps
//   [R12 vs R14] -> k_prep innocent, k_main flaw; audits x5 clean -> flaw is in
//   the never-passed combo: swapped-GEMM1/fused-GEMM2/cvt2-asm).
// R15: rebuild from PINNED pieces only. GEMM1 = R8 orientation (A=Q, B=K,
//   D[m=quad*4+r][n=l15]) but waves n-partitioned and K/asq streamed per-lane
//   from global (no ktile staging, no global_load_lds). P exchanged via small
//   LDS tile (R8 layout, pitch 72). GEMM2 = R9's exact pinned pattern (mv fp32
//   regs -> f2b pack8, P b128 from LDS). Denominator via atomicAdd dn[64].
//   No inline asm (m240). k_prep = R8-proven gather.

typedef unsigned short ushort_t;
typedef unsigned int uint_t;
typedef __attribute__((ext_vector_type(8))) short short8;
typedef __attribute__((ext_vector_type(4))) float floatx4;

#define MFMA16(a, b, c) __builtin_amdgcn_mfma_f32_16x16x32_bf16((a), (b), (c), 0, 0, 0)

__device__ __forceinline__ ushort_t f2b(float f) {
    uint_t b = __float_as_uint(f);
    b += 0x7FFFu + ((b >> 16) & 1u);   // RNE to bf16
    return (ushort_t)(b >> 16);
}

__device__ __forceinline__ short8 pack8(floatx4 a, floatx4 b) {
    short8 r;
    r[0] = (short)f2b(a[0]); r[1] = (short)f2b(a[1]);
    r[2] = (short)f2b(a[2]); r[3] = (short)f2b(a[3]);
    r[4] = (short)f2b(b[0]); r[5] = (short)f2b(b[1]);
    r[6] = (short)f2b(b[2]); r[7] = (short)f2b(b[3]);
    return r;
}

#define BB 4
#define CK 64
#define NN 8192
#define MM 1024
#define CV 512
#define NSTEP 128     // 64-token steps over full n-range

// ---- module-scope scratch (fully rewritten every call) ----
__device__ __align__(16) ushort_t g_mkT[BB * NN * CK];   // 4 MiB  bf16 mk^T [b][n][c]
__device__ __align__(16) float    g_asq8[BB * NN];       // 128 KiB (sum mk^2)/8

// ---------------------------------------------------------------------------
// K0 (R8/R9-proven): g_mkT[b][n][c] = bf16(mk[b][c][n]); g_asq8 = (sum mk^2)/8.
// ---------------------------------------------------------------------------
__global__ __launch_bounds__(256) void k_prep(const float* __restrict__ mk) {
    int t = blockIdx.x * 256 + threadIdx.x;   // 0 .. B*N-1
    int b = t >> 13;
    int n = t & (NN - 1);
    const float* src = mk + (size_t)b * CK * NN + n;
    ushort_t* dst = g_mkT + (size_t)t * CK;
    float acc = 0.f;
#pragma unroll
    for (int g = 0; g < 8; g++) {
        float f[8];
#pragma unroll
        for (int i = 0; i < 8; i++) {
            f[i] = src[(size_t)(g * 8 + i) * NN];
            acc += f[i] * f[i];
        }
        uint4 q;
        q.x = (uint_t)f2b(f[0]) | ((uint_t)f2b(f[1]) << 16);
        q.y = (uint_t)f2b(f[2]) | ((uint_t)f2b(f[3]) << 16);
        q.z = (uint_t)f2b(f[4]) | ((uint_t)f2b(f[5]) << 16);
        q.w = (uint_t)f2b(f[6]) | ((uint_t)f2b(f[7]) << 16);
        *(uint4*)(dst + g * 8) = q;
    }
    g_asq8[t] = acc * 0.125f;
}

// ---------------------------------------------------------------------------
// K1: grid 512 = mt16(16) x cs(8) x b(4); block 256 = 4 waves.
// Per 64-token step (wave w owns n-strip step*64 + w*16 + l15 for GEMM1):
//   GEMM1 (R8 orientation): A=Q-frags regs (row m=l15, k=quad*8+j),
//     B=K per-lane 16B global loads (col n=l15, k=quad*8+j) ->
//     D[m_loc=quad*4+r][n=l15]; p=exp(d/4 - asq[n]); f2b -> lds_p[m][n] (72).
//   barrier.
//   GEMM2 (R9-pinned): A=mv fp32 regs (row c=l15, k->n=kc*32+quad*8+j) f2b-
//     packed; B=P b128 from lds_p[(mt*16+l15)*72 + kc*32+quad*8] ->
//     acc[mt] (D row c_loc=quad*4+r, col m=mt*16+l15). Wave owns c-strip
//     c0+w*16. barrier.
// All global loads per-lane 16B, register double-buffered one step ahead.
// Epilogue: dpart shfl-reduce over l15, atomicAdd dn[64] across waves,
// normalize, direct store (each wave owns its c-rows).
// ---------------------------------------------------------------------------

#define STEP(KC0, KC1, AC, MC0, MC1, MC2, MC3, KN0, KN1, AN, MN0, MN1, MN2, MN3, stepv) do { \
    if ((stepv) + 1 < NSTEP) {                                                  \
        size_t no = (size_t)((stepv) + 1) * 64;                                 \
        const ushort_t* kp = kbase + no * CK;                                   \
        KN0 = *(const short8*)kp;                                               \
        KN1 = *(const short8*)(kp + 32);                                        \
        AN  = asbase[no];                                                       \
        MN0 = *(const floatx4*)(mvbase + no);                                   \
        MN1 = *(const floatx4*)(mvbase + no + 4);                               \
        MN2 = *(const floatx4*)(mvbase + no + 32);                              \
        MN3 = *(const floatx4*)(mvbase + no + 36);                              \
    }                                                                           \
    _Pragma("unroll")                                                           \
    for (int mt = 0; mt < 4; mt++) {                                            \
        floatx4 d = (floatx4){0.f, 0.f, 0.f, 0.f};                              \
        d = MFMA16(qb0[mt], KC0, d);                                            \
        d = MFMA16(qb1[mt], KC1, d);                                            \
        _Pragma("unroll")                                                       \
        for (int r = 0; r < 4; r++) {                                           \
            float p = __expf(d[r] * 0.25f - AC);                                \
            dpart[mt][r] += p;                                                  \
            lds_p[(mt * 16 + quad * 4 + r) * 72 + w * 16 + l15] = f2b(p);       \
        }                                                                       \
    }                                                                           \
    __syncthreads();   /* P tile complete */                                    \
    {                                                                           \
        short8 va0 = pack8(MC0, MC1);                                           \
        short8 va1 = pack8(MC2, MC3);                                           \
        _Pragma("unroll")                                                       \
        for (int mt = 0; mt < 4; mt++) {                                        \
            short8 pb0 = *(const short8*)&lds_p[(mt * 16 + l15) * 72 + quad * 8];        \
            short8 pb1 = *(const short8*)&lds_p[(mt * 16 + l15) * 72 + 32 + quad * 8];   \
            acc[mt] = MFMA16(va0, pb0, acc[mt]);                                \
            acc[mt] = MFMA16(va1, pb1, acc[mt]);                                \
        }                                                                       \
    }                                                                           \
    __syncthreads();   /* P consumed before next overwrite */                   \
} while (0)

__global__ __launch_bounds__(256, 2) void k_main(const float* __restrict__ qk,
                                                 const float* __restrict__ mv,
                                                 float* __restrict__ out) {
    __shared__ __align__(16) ushort_t lds_p[64 * 72];   // 9 KiB, P [m_loc][n_loc]
    __shared__ float dn[64];                            // denom per m_loc

    int bx = blockIdx.x;
    int mt16 = bx >> 5;          // 0..15
    int cs = (bx >> 2) & 7;      // 0..7  (bx%8 const per (cs,b): XCD grouping)
    int b = bx & 3;              // 0..3
    int c0 = cs * 64;
    int m0 = mt16 * 64;

    int tid = threadIdx.x;
    int w = tid >> 6;
    int lane = tid & 63;
    int quad = lane >> 4;
    int l15 = lane & 15;

    if (tid < 64) dn[tid] = 0.f;   // ordered before epilogue by loop barriers

    // ---- Q fragments: 4 m-tiles x K=64 (A-operand rows m = mt*16 + l15) ----
    short8 qb0[4], qb1[4];
#pragma unroll
    for (int mt = 0; mt < 4; mt++) {
#pragma unroll
        for (int j = 0; j < 8; j++) {
            qb0[mt][j] = (short)f2b(qk[(size_t)(b * CK + quad * 8 + j) * MM + m0 + mt * 16 + l15]);
            qb1[mt][j] = (short)f2b(qk[(size_t)(b * CK + 32 + quad * 8 + j) * MM + m0 + mt * 16 + l15]);
        }
    }

    // ---- per-lane stream bases ----
    const ushort_t* kbase  = g_mkT + ((size_t)b * NN + w * 16 + l15) * CK + quad * 8;
    const float*    asbase = g_asq8 + (size_t)b * NN + w * 16 + l15;
    const float*    mvbase = mv + ((size_t)(b * CV + c0 + w * 16 + l15)) * NN + quad * 8;

    floatx4 acc[4];
#pragma unroll
    for (int i = 0; i < 4; i++) acc[i] = (floatx4){0.f, 0.f, 0.f, 0.f};
    float dpart[4][4];
#pragma unroll
    for (int i = 0; i < 4; i++)
#pragma unroll
        for (int j = 0; j < 4; j++) dpart[i][j] = 0.f;

    // ---- prologue: step-0 operands into set A ----
    short8 kA0, kA1, kB0, kB1;
    floatx4 mA0, mA1, mA2, mA3, mB0, mB1, mB2, mB3;
    float aA, aB;
    kA0 = *(const short8*)kbase;
    kA1 = *(const short8*)(kbase + 32);
    aA  = *asbase;
    mA0 = *(const floatx4*)(mvbase);
    mA1 = *(const floatx4*)(mvbase + 4);
    mA2 = *(const floatx4*)(mvbase + 32);
    mA3 = *(const floatx4*)(mvbase + 36);

    for (int sp = 0; sp < NSTEP / 2; sp++) {
        STEP(kA0, kA1, aA, mA0, mA1, mA2, mA3, kB0, kB1, aB, mB0, mB1, mB2, mB3, sp * 2);
        STEP(kB0, kB1, aB, mB0, mB1, mB2, mB3, kA0, kA1, aA, mA0, mA1, mA2, mA3, sp * 2 + 1);
    }

    // ---- epilogue: denominator (reduce over l15, cross-wave atomicAdd) ----
#pragma unroll
    for (int mt = 0; mt < 4; mt++) {
#pragma unroll
        for (int r = 0; r < 4; r++) {
            float s = dpart[mt][r];
            s += __shfl_xor(s, 1, 64);
            s += __shfl_xor(s, 2, 64);
            s += __shfl_xor(s, 4, 64);
            s += __shfl_xor(s, 8, 64);
            if (l15 == 0) atomicAdd(&dn[mt * 16 + quad * 4 + r], s);
        }
    }
    __syncthreads();

    float rdm[4];
#pragma unroll
    for (int mt = 0; mt < 4; mt++) rdm[mt] = 1.0f / dn[mt * 16 + l15];
#pragma unroll
    for (int mt = 0; mt < 4; mt++) {
#pragma unroll
        for (int r = 0; r < 4; r++) {
            size_t o = (size_t)(b * CV + c0 + w * 16 + quad * 4 + r) * MM
                     + m0 + mt * 16 + l15;
            out[o] = acc[mt][r] * rdm[mt];
        }
    }
}

// ---------------------------------------------------------------------------
// launch — inputs identified BY SIZE.
// ---------------------------------------------------------------------------
extern "C" void kernel_launch(void* const* d_in, const int* in_sizes, int n_in,
                              void* d_out, int out_size, void* d_ws, size_t ws_size,
                              hipStream_t stream) {
    const float* mk = nullptr;   // 2,097,152
    const float* qk = nullptr;   //   262,144
    const float* mv = nullptr;   // 16,777,216
    for (int i = 0; i < n_in; i++) {
        if (in_sizes[i] == BB * CK * NN)      mk = (const float*)d_in[i];
        else if (in_sizes[i] == BB * CK * MM) qk = (const float*)d_in[i];
        else if (in_sizes[i] == BB * CV * NN) mv = (const float*)d_in[i];
    }
    float* out = (float*)d_out;
    (void)d_ws; (void)ws_size; (void)out_size;

    k_prep<<<(BB * NN) / 256, 256, 0, stream>>>(mk);
    k_main<<<16 * 8 * BB, 256, 0, stream>>>(qk, mv, out);
}

// Round 8
// 270.382 us; speedup vs baseline: 1.0790x; 1.0050x over previous
//
#include <hip/hip_runtime.h>

// MemoryReader: B=4, CK=64, N=8192, M=1024, CV=512. Inputs fp32, output fp32.
// logits s[n,m] = (2*mk.qk - |mk|^2)/8; softmax over n; out = mv @ P.
// R8: 197us k_main PASSED. R9: 228us PASSED. R10-R14: LDS-free k_main failed
//   deterministically (never-passed combo of swapped-GEMM1/fused-GEMM2/cvt asm).
// R15: PASSED 201us k_main — rebuilt from pinned pieces: GEMM1 A=Q,B=K(streamed
//   per-lane from g_mkT), P via 9KB LDS tile, GEMM2 = R9 pack8 + P b128.
//   Post-mortem: all pipes idle (Mfma 14/VALU 37/HBM 2.4%), 3770 cy/step vs
//   <1500 accountable -> fence-bound: __syncthreads = vmcnt(0) drain, and our
//   same-step register prefetches are forcibly drained at barrier1 (2 fences/step).
// R16: single change — loop barriers become {s_waitcnt lgkmcnt(0); s_barrier}
//   (raw builtin, no vmcnt drain). Legal because NO global->LDS traffic exists:
//   all global loads are register loads, auto-guarded by per-register waitcnt
//   before use (T4/m218 counted-vmcnt regime). lgkmcnt(0) keeps P-store/read
//   ordering; "memory" clobber pins DS ops around the barrier.

typedef unsigned short ushort_t;
typedef unsigned int uint_t;
typedef __attribute__((ext_vector_type(8))) short short8;
typedef __attribute__((ext_vector_type(4))) float floatx4;

#define MFMA16(a, b, c) __builtin_amdgcn_mfma_f32_16x16x32_bf16((a), (b), (c), 0, 0, 0)

// Raw barrier: DS-ordering only; global register loads stay in flight.
#define BARRIER_DS() do {                                          \
    asm volatile("s_waitcnt lgkmcnt(0)" ::: "memory");             \
    __builtin_amdgcn_s_barrier();                                  \
} while (0)

__device__ __forceinline__ ushort_t f2b(float f) {
    uint_t b = __float_as_uint(f);
    b += 0x7FFFu + ((b >> 16) & 1u);   // RNE to bf16
    return (ushort_t)(b >> 16);
}

__device__ __forceinline__ short8 pack8(floatx4 a, floatx4 b) {
    short8 r;
    r[0] = (short)f2b(a[0]); r[1] = (short)f2b(a[1]);
    r[2] = (short)f2b(a[2]); r[3] = (short)f2b(a[3]);
    r[4] = (short)f2b(b[0]); r[5] = (short)f2b(b[1]);
    r[6] = (short)f2b(b[2]); r[7] = (short)f2b(b[3]);
    return r;
}

#define BB 4
#define CK 64
#define NN 8192
#define MM 1024
#define CV 512
#define NSTEP 128     // 64-token steps over full n-range

// ---- module-scope scratch (fully rewritten every call) ----
__device__ __align__(16) ushort_t g_mkT[BB * NN * CK];   // 4 MiB  bf16 mk^T [b][n][c]
__device__ __align__(16) float    g_asq8[BB * NN];       // 128 KiB (sum mk^2)/8

// ---------------------------------------------------------------------------
// K0 (R8/R9-proven): g_mkT[b][n][c] = bf16(mk[b][c][n]); g_asq8 = (sum mk^2)/8.
// ---------------------------------------------------------------------------
__global__ __launch_bounds__(256) void k_prep(const float* __restrict__ mk) {
    int t = blockIdx.x * 256 + threadIdx.x;   // 0 .. B*N-1
    int b = t >> 13;
    int n = t & (NN - 1);
    const float* src = mk + (size_t)b * CK * NN + n;
    ushort_t* dst = g_mkT + (size_t)t * CK;
    float acc = 0.f;
#pragma unroll
    for (int g = 0; g < 8; g++) {
        float f[8];
#pragma unroll
        for (int i = 0; i < 8; i++) {
            f[i] = src[(size_t)(g * 8 + i) * NN];
            acc += f[i] * f[i];
        }
        uint4 q;
        q.x = (uint_t)f2b(f[0]) | ((uint_t)f2b(f[1]) << 16);
        q.y = (uint_t)f2b(f[2]) | ((uint_t)f2b(f[3]) << 16);
        q.z = (uint_t)f2b(f[4]) | ((uint_t)f2b(f[5]) << 16);
        q.w = (uint_t)f2b(f[6]) | ((uint_t)f2b(f[7]) << 16);
        *(uint4*)(dst + g * 8) = q;
    }
    g_asq8[t] = acc * 0.125f;
}

// ---------------------------------------------------------------------------
// K1: grid 512 = mt16(16) x cs(8) x b(4); block 256 = 4 waves.
// Per 64-token step (wave w owns n-strip step*64 + w*16 + l15 for GEMM1):
//   GEMM1 (R8 orientation): A=Q-frags regs (row m=l15, k=quad*8+j),
//     B=K per-lane 16B global loads (col n=l15, k=quad*8+j) ->
//     D[m_loc=quad*4+r][n=l15]; p=exp(d/4 - asq[n]); f2b -> lds_p[m][n] (72).
//   BARRIER_DS.
//   GEMM2 (R9-pinned): A=mv fp32 regs (row c=l15, k->n=kc*32+quad*8+j) f2b-
//     packed; B=P b128 from lds_p[(mt*16+l15)*72 + kc*32+quad*8] ->
//     acc[mt] (D row c_loc=quad*4+r, col m=mt*16+l15). Wave owns c-strip
//     c0+w*16. BARRIER_DS.
// All global loads per-lane 16B, register double-buffered one step ahead;
// loads stay in flight across barriers (no vmcnt drain).
// Epilogue: dpart shfl-reduce over l15, atomicAdd dn[64] across waves,
// normalize, direct store (each wave owns its c-rows).
// ---------------------------------------------------------------------------

#define STEP(KC0, KC1, AC, MC0, MC1, MC2, MC3, KN0, KN1, AN, MN0, MN1, MN2, MN3, stepv) do { \
    if ((stepv) + 1 < NSTEP) {                                                  \
        size_t no = (size_t)((stepv) + 1) * 64;                                 \
        const ushort_t* kp = kbase + no * CK;                                   \
        KN0 = *(const short8*)kp;                                               \
        KN1 = *(const short8*)(kp + 32);                                        \
        AN  = asbase[no];                                                       \
        MN0 = *(const floatx4*)(mvbase + no);                                   \
        MN1 = *(const floatx4*)(mvbase + no + 4);                               \
        MN2 = *(const floatx4*)(mvbase + no + 32);                              \
        MN3 = *(const floatx4*)(mvbase + no + 36);                              \
    }                                                                           \
    _Pragma("unroll")                                                           \
    for (int mt = 0; mt < 4; mt++) {                                            \
        floatx4 d = (floatx4){0.f, 0.f, 0.f, 0.f};                              \
        d = MFMA16(qb0[mt], KC0, d);                                            \
        d = MFMA16(qb1[mt], KC1, d);                                            \
        _Pragma("unroll")                                                       \
        for (int r = 0; r < 4; r++) {                                           \
            float p = __expf(d[r] * 0.25f - AC);                                \
            dpart[mt][r] += p;                                                  \
            lds_p[(mt * 16 + quad * 4 + r) * 72 + w * 16 + l15] = f2b(p);       \
        }                                                                       \
    }                                                                           \
    BARRIER_DS();   /* P stores visible; global prefetch stays in flight */     \
    {                                                                           \
        short8 va0 = pack8(MC0, MC1);                                           \
        short8 va1 = pack8(MC2, MC3);                                           \
        _Pragma("unroll")                                                       \
        for (int mt = 0; mt < 4; mt++) {                                        \
            short8 pb0 = *(const short8*)&lds_p[(mt * 16 + l15) * 72 + quad * 8];        \
            short8 pb1 = *(const short8*)&lds_p[(mt * 16 + l15) * 72 + 32 + quad * 8];   \
            acc[mt] = MFMA16(va0, pb0, acc[mt]);                                \
            acc[mt] = MFMA16(va1, pb1, acc[mt]);                                \
        }                                                                       \
    }                                                                           \
    BARRIER_DS();   /* P consumed before next overwrite */                      \
} while (0)

__global__ __launch_bounds__(256, 2) void k_main(const float* __restrict__ qk,
                                                 const float* __restrict__ mv,
                                                 float* __restrict__ out) {
    __shared__ __align__(16) ushort_t lds_p[64 * 72];   // 9 KiB, P [m_loc][n_loc]
    __shared__ float dn[64];                            // denom per m_loc

    int bx = blockIdx.x;
    int mt16 = bx >> 5;          // 0..15
    int cs = (bx >> 2) & 7;      // 0..7  (bx%8 const per (cs,b): XCD grouping)
    int b = bx & 3;              // 0..3
    int c0 = cs * 64;
    int m0 = mt16 * 64;

    int tid = threadIdx.x;
    int w = tid >> 6;
    int lane = tid & 63;
    int quad = lane >> 4;
    int l15 = lane & 15;

    if (tid < 64) dn[tid] = 0.f;   // ordered before epilogue by loop barriers

    // ---- Q fragments: 4 m-tiles x K=64 (A-operand rows m = mt*16 + l15) ----
    short8 qb0[4], qb1[4];
#pragma unroll
    for (int mt = 0; mt < 4; mt++) {
#pragma unroll
        for (int j = 0; j < 8; j++) {
            qb0[mt][j] = (short)f2b(qk[(size_t)(b * CK + quad * 8 + j) * MM + m0 + mt * 16 + l15]);
            qb1[mt][j] = (short)f2b(qk[(size_t)(b * CK + 32 + quad * 8 + j) * MM + m0 + mt * 16 + l15]);
        }
    }

    // ---- per-lane stream bases ----
    const ushort_t* kbase  = g_mkT + ((size_t)b * NN + w * 16 + l15) * CK + quad * 8;
    const float*    asbase = g_asq8 + (size_t)b * NN + w * 16 + l15;
    const float*    mvbase = mv + ((size_t)(b * CV + c0 + w * 16 + l15)) * NN + quad * 8;

    floatx4 acc[4];
#pragma unroll
    for (int i = 0; i < 4; i++) acc[i] = (floatx4){0.f, 0.f, 0.f, 0.f};
    float dpart[4][4];
#pragma unroll
    for (int i = 0; i < 4; i++)
#pragma unroll
        for (int j = 0; j < 4; j++) dpart[i][j] = 0.f;

    // ---- prologue: step-0 operands into set A ----
    short8 kA0, kA1, kB0, kB1;
    floatx4 mA0, mA1, mA2, mA3, mB0, mB1, mB2, mB3;
    float aA, aB;
    kA0 = *(const short8*)kbase;
    kA1 = *(const short8*)(kbase + 32);
    aA  = *asbase;
    mA0 = *(const floatx4*)(mvbase);
    mA1 = *(const floatx4*)(mvbase + 4);
    mA2 = *(const floatx4*)(mvbase + 32);
    mA3 = *(const floatx4*)(mvbase + 36);

    for (int sp = 0; sp < NSTEP / 2; sp++) {
        STEP(kA0, kA1, aA, mA0, mA1, mA2, mA3, kB0, kB1, aB, mB0, mB1, mB2, mB3, sp * 2);
        STEP(kB0, kB1, aB, mB0, mB1, mB2, mB3, kA0, kA1, aA, mA0, mA1, mA2, mA3, sp * 2 + 1);
    }

    // ---- epilogue: denominator (reduce over l15, cross-wave atomicAdd) ----
#pragma unroll
    for (int mt = 0; mt < 4; mt++) {
#pragma unroll
        for (int r = 0; r < 4; r++) {
            float s = dpart[mt][r];
            s += __shfl_xor(s, 1, 64);
            s += __shfl_xor(s, 2, 64);
            s += __shfl_xor(s, 4, 64);
            s += __shfl_xor(s, 8, 64);
            if (l15 == 0) atomicAdd(&dn[mt * 16 + quad * 4 + r], s);
        }
    }
    __syncthreads();

    float rdm[4];
#pragma unroll
    for (int mt = 0; mt < 4; mt++) rdm[mt] = 1.0f / dn[mt * 16 + l15];
#pragma unroll
    for (int mt = 0; mt < 4; mt++) {
#pragma unroll
        for (int r = 0; r < 4; r++) {
            size_t o = (size_t)(b * CV + c0 + w * 16 + quad * 4 + r) * MM
                     + m0 + mt * 16 + l15;
            out[o] = acc[mt][r] * rdm[mt];
        }
    }
}

// ---------------------------------------------------------------------------
// launch — inputs identified BY SIZE.
// ---------------------------------------------------------------------------
extern "C" void kernel_launch(void* const* d_in, const int* in_sizes, int n_in,
                              void* d_out, int out_size, void* d_ws, size_t ws_size,
                              hipStream_t stream) {
    const float* mk = nullptr;   // 2,097,152
    const float* qk = nullptr;   //   262,144
    const float* mv = nullptr;   // 16,777,216
    for (int i = 0; i < n_in; i++) {
        if (in_sizes[i] == BB * CK * NN)      mk = (const float*)d_in[i];
        else if (in_sizes[i] == BB * CK * MM) qk = (const float*)d_in[i];
        else if (in_sizes[i] == BB * CV * NN) mv = (const float*)d_in[i];
    }
    float* out = (float*)d_out;
    (void)d_ws; (void)ws_size; (void)out_size;

    k_prep<<<(BB * NN) / 256, 256, 0, stream>>>(mk);
    k_main<<<16 * 8 * BB, 256, 0, stream>>>(qk, mv, out);
}